// Round 9
// baseline (304.415 us; speedup 1.0000x reference)
//
#include <hip/hip_runtime.h>

// ---------------------------------------------------------------------------
// MatryoshkaAttention on MI355X (gfx950), bf16 MFMA pipeline. Round 15.
//
// Changes vs R14 (single variable):
//  - k_attn: s_setprio(1) around both MFMA clusters (QK^T h-loop, PV s/nc
//    loop) [T5]. ~3 blocks/CU co-resident, waves within a tile run
//    independent QK^T/softmax/PV chains -> scheduler role-diversity exists;
//    setprio biases the matrix pipe while sibling waves do VALU softmax.
//    (m191: +4-7% attn; m190 null only for lockstep GEMM.)
//  Everything else byte-identical to R14 (best: 298.5 us).
// ---------------------------------------------------------------------------

typedef short bf16x8 __attribute__((ext_vector_type(8)));
typedef float floatx4 __attribute__((ext_vector_type(4)));

__device__ __forceinline__ unsigned short f2bf(float f) {
  unsigned u = __builtin_bit_cast(unsigned, f);
  u += 0x7fffu + ((u >> 16) & 1u);           // RNE
  return (unsigned short)(u >> 16);
}

__device__ __forceinline__ void gload_lds16(const unsigned short* g, unsigned short* l) {
  __builtin_amdgcn_global_load_lds((const __attribute__((address_space(1))) unsigned int*)g,
                                   (__attribute__((address_space(3))) unsigned int*)l, 16, 0, 0);
}

// ---------------- 1. fused prep: cvt_x | pack_qkv(+corr) | pack_o ----------
// blocks [0,8192): x->bf16 ; [8192,17408): W_QKV pack ; [17408,20480): W_O.
__global__ __launch_bounds__(256) void k_prep(
    const float* __restrict__ x, unsigned short* __restrict__ X16,
    const float* __restrict__ WQ, const float* __restrict__ WK, const float* __restrict__ WV,
    const float* __restrict__ FK0, const float* __restrict__ PK0,
    const float* __restrict__ FV0, const float* __restrict__ PV0,
    const float* __restrict__ FK1, const float* __restrict__ PK1,
    const float* __restrict__ FV1, const float* __restrict__ PV1,
    unsigned short* __restrict__ WTQKV,
    const float* __restrict__ WO, unsigned short* __restrict__ WTO) {
  __shared__ float tile[32][33];
  __shared__ float Fs[32][9];
  __shared__ float Ps[8][32];
  const int bid = blockIdx.x;
  const int tid = threadIdx.x;
  if (bid < 8192) {                       // ---- x -> bf16 (float4 per thread)
    int i = bid * 256 + tid;
    float4 v = ((const float4*)x)[i];
    union { unsigned short u[4]; uint2 v2; } o;
    o.u[0] = f2bf(v.x); o.u[1] = f2bf(v.y); o.u[2] = f2bf(v.z); o.u[3] = f2bf(v.w);
    ((uint2*)X16)[i] = o.v2;
    return;
  }
  const int tx = tid & 31, ty = tid >> 5;
  if (bid < 17408) {                      // ---- W_QKV transpose + corrections
    int t = bid - 8192;
    int k0 = (t & 63) * 32, n0 = (t >> 6) * 32;
    const float* src; int nboff;
    if (n0 < 1536)      { src = WQ; nboff = n0; }
    else if (n0 < 3072) { src = WK; nboff = n0 - 1536; }
    else                { src = WV; nboff = n0 - 3072; }
#pragma unroll
    for (int j = 0; j < 4; ++j) {
      int kk = ty + j * 8;
      tile[kk][tx] = src[(size_t)(k0 + kk) * 1536 + nboff + tx];
    }
    int corrsel = 0; const float* Fsrc = nullptr; const float* Psrc = nullptr;
    int h = 0, d0 = 0, fs = 0, koff = 0;
    if (n0 >= 1536) {
      bool isK = (n0 < 3072);
      int np0 = isK ? (n0 - 1536) : (n0 - 3072);
      if (np0 < 256) {
        if (k0 >= 256) { corrsel = 1; Fsrc = isK ? FK0 : FV0; Psrc = isK ? PK0 : PV0;
                         h = np0 >> 6; d0 = np0 & 63; fs = 32; koff = k0 - 256; }
      } else if (np0 < 768) {
        if (k0 >= 1024) { corrsel = 1; Fsrc = isK ? FK1 : FV1; Psrc = isK ? PK1 : PV1;
                          h = (np0 - 256) >> 6; d0 = (np0 - 256) & 63; fs = 64; koff = k0 - 1024; }
      }
    }
    if (corrsel) {
      Fs[tid >> 3][tid & 7] = Fsrc[(size_t)(koff + (tid >> 3)) * fs + h * 8 + (tid & 7)];
      Ps[tid >> 5][tid & 31] = Psrc[h * 512 + (tid >> 5) * 64 + d0 + (tid & 31)];
    }
    __syncthreads();
#pragma unroll
    for (int j = 0; j < 4; ++j) {
      int nn = ty + j * 8;
      float v = tile[tx][nn];
      if (corrsel) {
        float c = 0.f;
#pragma unroll
        for (int r = 0; r < 8; ++r) c += Fs[tx][r] * Ps[r][nn];
        v += c;
      }
      WTQKV[(size_t)(n0 + nn) * 2048 + k0 + tx] = f2bf(v);
    }
  } else {                                // ---- W_O transpose
    int t = bid - 17408;
    int k0 = (t % 48) * 32, n0 = (t / 48) * 32;
#pragma unroll
    for (int j = 0; j < 4; ++j)
      tile[ty + j * 8][tx] = WO[(size_t)(k0 + ty + j * 8) * 2048 + n0 + tx];
    __syncthreads();
#pragma unroll
    for (int j = 0; j < 4; ++j)
      WTO[(size_t)(n0 + ty + j * 8) * 1536 + k0 + tx] = f2bf(tile[tx][ty + j * 8]);
  }
}

// ---------------- 4/6. GEMM BK=64, Keff per column block, XCD-chunked -------
// MODE 0: QKV (1152 blocks = 8 XCD x 144). Long class dispatches V-cols first.
//   Q/K cols (bn<3072) -> QK (LD 3072); V cols (bn>=3072) -> VT[b][d][t]
//   via in-LDS 64x64 transpose.
// MODE 1: out (512 blocks = 8 x 64) -> f32 C (LD 2048).
template <bool OUT_BF16, int MODE>
__global__ __launch_bounds__(256) void k_gemm_bt(const unsigned short* __restrict__ A,
                                                 const unsigned short* __restrict__ Bt,
                                                 void* __restrict__ C, int M, int N, int K,
                                                 unsigned short* __restrict__ VTout) {
  __shared__ unsigned short As[128 * 64];
  __shared__ unsigned short Bs[128 * 64];
  const int tid = threadIdx.x;
  const int wave = tid >> 6, lane = tid & 63;
  const int qd = lane >> 4, ln = lane & 15;
  const int idx = blockIdx.x;
  const int xcd = idx & 7, r = idx >> 3;
  int bx, by;
  if (MODE == 0) {
    if (r < 120) {                 // long: Keff=2048; scol inverted => V first
      int L = xcd * 120 + r;
      int scol = L / 192, q = L % 192;
      by = q / 6; bx = 6 + (4 - scol) * 6 + q % 6;
    } else {
      int ms = xcd * 24 + (r - 120);          // 0..191
      if (ms < 128) { bx = 2 + (ms & 3); by = ms >> 2; }   // mid: Keff=1024
      else          { int sh = ms - 128; bx = sh & 1; by = sh >> 1; } // short
    }
  } else {
    if (r < 32) {                  // long: Keff=1536, 256 blocks = 2 scol x (4bx x 32by)
      int L = xcd * 32 + r;
      int scol = L >> 7, q = L & 127;
      by = q >> 2; bx = 8 + scol * 4 + (q & 3);
    } else if (r < 56) {
      int m = xcd * 24 + (r - 32);            // 0..191, mid: Keff=768
      bx = 2 + m % 6; by = m / 6;
    } else {
      int sh = xcd * 8 + (r - 56);            // 0..63, short: Keff=256
      bx = sh & 1; by = sh >> 1;
    }
  }
  const int bm = by * 128, bn = bx * 128;
  const int wr = wave >> 1, wc = wave & 1;
  int Keff;
  if (MODE == 0) Keff = (bn < 256) ? 256 : (bn < 768 ? 1024 : 2048);
  else           Keff = (bn < 256) ? 256 : (bn < 1024 ? 768 : 1536);
  floatx4 acc[4][4];
#pragma unroll
  for (int i = 0; i < 4; ++i)
#pragma unroll
    for (int j = 0; j < 4; ++j) acc[i][j] = (floatx4){0.f, 0.f, 0.f, 0.f};
  const int rl = lane >> 3;                        // row mod 8
  const int sg = (lane & 7) ^ rl;                  // swizzled source group
  const unsigned short* gA = A + (size_t)(bm + wave * 32 + rl) * K + sg * 8;
  const unsigned short* gB = Bt + (size_t)(bn + wave * 32 + rl) * K + sg * 8;
  unsigned short* lA = As + wave * 2048;
  unsigned short* lB = Bs + wave * 2048;
  const int l7 = ln & 7;
  for (int k0 = 0; k0 < Keff; k0 += 64) {
    __syncthreads();
#pragma unroll
    for (int i = 0; i < 4; ++i) {
      gload_lds16(gA + (size_t)8 * i * K + k0, lA + i * 512);
      gload_lds16(gB + (size_t)8 * i * K + k0, lB + i * 512);
    }
    __syncthreads();
#pragma unroll
    for (int h = 0; h < 2; ++h) {
      bf16x8 af[4], bfr[4];
#pragma unroll
      for (int mi = 0; mi < 4; ++mi)
        af[mi] = *(const bf16x8*)(As + (wr * 64 + mi * 16 + ln) * 64 + ((h * 4 + qd) ^ l7) * 8);
#pragma unroll
      for (int ni = 0; ni < 4; ++ni)
        bfr[ni] = *(const bf16x8*)(Bs + (wc * 64 + ni * 16 + ln) * 64 + ((h * 4 + qd) ^ l7) * 8);
#pragma unroll
      for (int mi = 0; mi < 4; ++mi)
#pragma unroll
        for (int ni = 0; ni < 4; ++ni)
          acc[mi][ni] = __builtin_amdgcn_mfma_f32_16x16x32_bf16(af[mi], bfr[ni], acc[mi][ni], 0, 0, 0);
    }
  }
  if (MODE == 0 && bn >= 3072) {
    // ---- V block: transpose 128x128 in LDS (per-wave 64x64), store VT[b][d][t].
    __syncthreads();                       // all waves done reading As/Bs
    unsigned short* tw = (wave < 2) ? (As + wave * 4096) : (Bs + (wave - 2) * 4096);
#pragma unroll
    for (int mi = 0; mi < 4; ++mi)
#pragma unroll
      for (int ni = 0; ni < 4; ++ni) {
        union { unsigned short u[4]; uint2 v; } p;
#pragma unroll
        for (int rr = 0; rr < 4; ++rr) p.u[rr] = f2bf(acc[mi][ni][rr]);
        int d = ni * 16 + ln;
        int c = mi * 2 + (qd >> 1);
        *(uint2*)(tw + d * 64 + ((c ^ (ln & 7)) << 3) + ((qd & 1) << 2)) = p.v;
      }
    __asm__ volatile("s_waitcnt lgkmcnt(0)" ::: "memory");
    const int a = lane >> 3, bl = lane & 7;
    const int bb = bm >> 10, tt0 = bm & 1023;
    const int dbase = (bn - 3072) + wc * 64;
    const int tg = tt0 + wr * 64 + bl * 8;
#pragma unroll
    for (int i = 0; i < 8; ++i) {
      int d = a + 8 * i;
      uint4 v = *(const uint4*)(tw + d * 64 + ((bl ^ a) << 3));
      *(uint4*)(VTout + ((size_t)(bb * 1536 + dbase + d)) * 1024 + tg) = v;
    }
  } else {
#pragma unroll
    for (int mi = 0; mi < 4; ++mi)
#pragma unroll
      for (int r2 = 0; r2 < 4; ++r2) {
        int row = bm + wr * 64 + mi * 16 + qd * 4 + r2;
#pragma unroll
        for (int ni = 0; ni < 4; ++ni) {
          int col = bn + wc * 64 + ni * 16 + ln;
          if (OUT_BF16)
            ((unsigned short*)C)[(size_t)row * N + col] = f2bf(acc[mi][ni][r2]);
          else
            ((float*)C)[(size_t)row * N + col] = acc[mi][ni][r2];
        }
      }
  }
}

// ---------------- 5. causal flash attention, 128q x 128k tiles --------------
// grid (24 heads, 4 batch, 8 qtiles): qtile slowest => all 8 qtiles of a
// (head,batch) on one XCD (96%8==0). qb=7-z: LPT. QK buffer LD 3072.
// T14 async-stage (reg-staged K/V, issue-early) + T5 setprio on MFMA clusters.
#define LDP 136
__global__ __launch_bounds__(256) void k_attn(const unsigned short* __restrict__ QKV,
                                              const unsigned short* __restrict__ VT,
                                              unsigned short* __restrict__ Oout) {
  __shared__ unsigned short Ks[128 * 64];     // [key][d], 8-grp XOR swizzle
  __shared__ unsigned short VTs[64 * 128];    // [d][key], 16-grp XOR swizzle
  __shared__ unsigned short Pl[4][16 * LDP];  // wave-private P staging
  const int tid = threadIdx.x;
  const int wave = tid >> 6, lane = tid & 63;
  const int qd = lane >> 4, ln = lane & 15;
  const int gh = blockIdx.x, b = blockIdx.y;
  const int qb = 7 - (int)blockIdx.z;                    // big qtiles first
  const int T = 1024, LD = 3072;
  const size_t rowbase = (size_t)b * T * LD;
  const int qcol = 64 * gh, kcol = 1536 + 64 * gh;
  const unsigned short* VTg = VT + ((size_t)b * 1536 + 64 * gh) * 1024;
  const float SCALE = 0.18033688f;  // 1/sqrt(64) * log2(e)
  const int q0 = qb * 128 + wave * 16;       // frag j adds j*64

  bf16x8 aq[2][2];
#pragma unroll
  for (int j = 0; j < 2; ++j) {
    const unsigned short* qp = QKV + rowbase + (size_t)(q0 + j * 64 + ln) * LD + qcol;
    aq[j][0] = *(const bf16x8*)(qp + qd * 8);
    aq[j][1] = *(const bf16x8*)(qp + 32 + qd * 8);
  }
  floatx4 Oacc[2][4];
#pragma unroll
  for (int j = 0; j < 2; ++j)
#pragma unroll
    for (int i = 0; i < 4; ++i) Oacc[j][i] = (floatx4){0.f, 0.f, 0.f, 0.f};
  float l_lane[2] = {0.f, 0.f};

  // K staging: wave owns rows [wave*32, +32); V staging: d-rows [wave*16,+16)
  const int rk = lane >> 3;                   // 0..7
  const int gk = ((lane & 7) ^ rk) * 8;       // swizzled source group (8-grp)
  const unsigned short* gK = QKV + rowbase + (size_t)(wave * 32 + rk) * LD + kcol + gk;
  unsigned short* lK = Ks + wave * 32 * 64;
  const int rv = lane >> 4;                   // 0..3
  const int cv = lane & 15;
  unsigned short* lV = VTs + wave * 16 * 128;
  const unsigned short* gVrow[4];
  int gvcol[4];
#pragma unroll
  for (int i = 0; i < 4; ++i) {
    int d = wave * 16 + 4 * i + rv;
    gVrow[i] = VTg + (size_t)d * 1024;
    gvcol[i] = (cv ^ (4 * i + rv)) * 8;       // 16-grp swizzle by d&15
  }
  const int l7 = ln & 7;

  // ---- reg-staged tiles (time-shared reg block, T14/T16)
  bf16x8 kr[4], vr[4];
#pragma unroll
  for (int i = 0; i < 4; ++i) {
    kr[i] = *(const bf16x8*)(gK + (size_t)(8 * i) * LD);
    vr[i] = *(const bf16x8*)(gVrow[i] + gvcol[i]);
  }

  for (int jt = 0; jt <= qb; ++jt) {
    const int jk = jt * 128;
    const bool diag = (jt == qb);
    __syncthreads();                        // prior reads done; vmcnt drained
#pragma unroll
    for (int i = 0; i < 4; ++i) {
      *(bf16x8*)(lK + i * 512 + lane * 8) = kr[i];
      *(bf16x8*)(lV + i * 512 + lane * 8) = vr[i];
    }
    __syncthreads();                        // publish
    if (jt < qb) {
      const int nk = jk + 128;
#pragma unroll
      for (int i = 0; i < 4; ++i) {
        kr[i] = *(const bf16x8*)(gK + (size_t)(nk + 8 * i) * LD);
        vr[i] = *(const bf16x8*)(gVrow[i] + nk + gvcol[i]);
      }
    }

#pragma unroll
    for (int j = 0; j < 2; ++j) {
      const bool dj0 = diag && (j == 0);
      const int hmax = dj0 ? 4 : 8;
      // S^T = K Q^T : A = K[key][d] (frag h = keys h*16..+16), B = Q
      floatx4 Sc[8];
      __builtin_amdgcn_s_setprio(1);
#pragma unroll
      for (int h = 0; h < 8; ++h) {
        if (h >= hmax) continue;
        Sc[h] = (floatx4){0.f, 0.f, 0.f, 0.f};
        bf16x8 a0 = *(const bf16x8*)(Ks + (h * 16 + ln) * 64 + (qd ^ l7) * 8);
        bf16x8 a1 = *(const bf16x8*)(Ks + (h * 16 + ln) * 64 + ((4 + qd) ^ l7) * 8);
        Sc[h] = __builtin_amdgcn_mfma_f32_16x16x32_bf16(a0, aq[j][0], Sc[h], 0, 0, 0);
        Sc[h] = __builtin_amdgcn_mfma_f32_16x16x32_bf16(a1, aq[j][1], Sc[h], 0, 0, 0);
      }
      __builtin_amdgcn_s_setprio(0);
      const int qrow = q0 + j * 64 + ln;
      unsigned short* pw = Pl[wave];
#pragma unroll
      for (int h = 0; h < 8; ++h) {
        if (h >= hmax) continue;
        union { unsigned short u[4]; uint2 v; } pk;
#pragma unroll
        for (int r = 0; r < 4; ++r) {
          float v = fminf(Sc[h][r] * SCALE, 80.f);
          float p = __builtin_amdgcn_exp2f(v);
          if (diag && (j == 0 || h >= 4)) {
            int key = jk + h * 16 + qd * 4 + r;
            if (key > qrow) p = 0.f;
          }
          l_lane[j] += p;
          pk.u[r] = f2bf(p);
        }
        *(uint2*)(pw + ln * LDP + h * 16 + qd * 4) = pk.v;
      }
      __asm__ volatile("s_waitcnt lgkmcnt(0)" ::: "memory");
      const int smax = dj0 ? 2 : 4;
      bf16x8 pa[4];
#pragma unroll
      for (int s = 0; s < 4; ++s) {
        if (s >= smax) continue;
        pa[s] = *(const bf16x8*)(pw + ln * LDP + s * 32 + qd * 8);
      }
      __builtin_amdgcn_s_setprio(1);
#pragma unroll
      for (int nc = 0; nc < 4; ++nc) {
        const int d = nc * 16 + ln;
#pragma unroll
        for (int s = 0; s < 4; ++s) {
          if (s >= smax) continue;
          bf16x8 bv = *(const bf16x8*)(VTs + d * 128 + (((s * 4 + qd) ^ ln) & 15) * 8);
          Oacc[j][nc] = __builtin_amdgcn_mfma_f32_16x16x32_bf16(pa[s], bv, Oacc[j][nc], 0, 0, 0);
        }
      }
      __builtin_amdgcn_s_setprio(0);
    }
  }
  // l: sum the 4 qd-groups per ln, then normalize + store
#pragma unroll
  for (int j = 0; j < 2; ++j) {
    float l = l_lane[j];
    l += __shfl_xor(l, 16, 64);
    l += __shfl_xor(l, 32, 64);
#pragma unroll
    for (int r = 0; r < 4; ++r) {
      float inv = 1.0f / __shfl(l, qd * 4 + r, 64);
      size_t row = (size_t)b * T + q0 + j * 64 + qd * 4 + r;
#pragma unroll
      for (int nc = 0; nc < 4; ++nc)
        Oout[row * 1536 + 64 * gh + nc * 16 + ln] = f2bf(Oacc[j][nc][r] * inv);
    }
  }
}

// ---------------------------------------------------------------------------
extern "C" void kernel_launch(void* const* d_in, const int* in_sizes, int n_in,
                              void* d_out, int out_size, void* d_ws, size_t ws_size,
                              hipStream_t stream) {
  (void)in_sizes; (void)n_in; (void)out_size; (void)ws_size;
  const float* x   = (const float*)d_in[0];
  const float* WQ  = (const float*)d_in[1];
  const float* WK  = (const float*)d_in[2];
  const float* WV  = (const float*)d_in[3];
  const float* WO  = (const float*)d_in[4];
  const float* FK0 = (const float*)d_in[5];
  const float* PK0 = (const float*)d_in[6];
  const float* FV0 = (const float*)d_in[7];
  const float* PV0 = (const float*)d_in[8];
  const float* FK1 = (const float*)d_in[9];
  const float* PK1 = (const float*)d_in[10];
  const float* FV1 = (const float*)d_in[11];
  const float* PV1 = (const float*)d_in[12];

  char* ws = (char*)d_ws;
  unsigned short* X16   = (unsigned short*)(ws + 0);          // 16.0 MB
  unsigned short* WTQKV = (unsigned short*)(ws + 16777216);   // 18.0 MB
  unsigned short* QK    = (unsigned short*)(ws + 35651584);   // 24.0 MB (LD 3072)
  unsigned short* VT    = (unsigned short*)(ws + 60817408);   // 12.0 MB
  unsigned short* ATT   = (unsigned short*)(ws + 73400320);   // 12.0 MB
  unsigned short* WTO   = (unsigned short*)(ws + 85983232);   //  6.0 MB

  k_prep<<<20480, 256, 0, stream>>>(x, X16, WQ, WK, WV,
                                    FK0, PK0, FV0, PV0, FK1, PK1, FV1, PV1,
                                    WTQKV, WO, WTO);
  k_gemm_bt<true, 0><<<1152, 256, 0, stream>>>(X16, WTQKV, QK, 4096, 3072, 2048, VT);
  k_attn<<<dim3(24, 4, 8), 256, 0, stream>>>(QK, VT, ATT);
  k_gemm_bt<false, 1><<<512, 256, 0, stream>>>(ATT, WTO, d_out, 4096, 2048, 1536, nullptr);
}

// Round 10
// 296.013 us; speedup vs baseline: 1.0284x; 1.0284x over previous
//
#include <hip/hip_runtime.h>

// ---------------------------------------------------------------------------
// MatryoshkaAttention on MI355X (gfx950), bf16 MFMA pipeline. Round 16.
//
// Changes vs R15:
//  - k_attn: setprio REVERTED (R15: 298.5 -> 304.4; MFMA-boost starved the
//    VALU/TRANS softmax, which is the critical pipe here).
//  - k_attn: softmax P-pack via v_cvt_pk_bf16_f32 (inline asm, RNE — same
//    rounding as f2bf): 2 ops per h instead of ~24 bit-twiddle VALU ops.
//    Direct attack on the softmax-VALU bottleneck identified by R15.
//  Everything else byte-identical to R14 (best: 298.5 us).
// ---------------------------------------------------------------------------

typedef short bf16x8 __attribute__((ext_vector_type(8)));
typedef float floatx4 __attribute__((ext_vector_type(4)));

__device__ __forceinline__ unsigned short f2bf(float f) {
  unsigned u = __builtin_bit_cast(unsigned, f);
  u += 0x7fffu + ((u >> 16) & 1u);           // RNE
  return (unsigned short)(u >> 16);
}

__device__ __forceinline__ void gload_lds16(const unsigned short* g, unsigned short* l) {
  __builtin_amdgcn_global_load_lds((const __attribute__((address_space(1))) unsigned int*)g,
                                   (__attribute__((address_space(3))) unsigned int*)l, 16, 0, 0);
}

// ---------------- 1. fused prep: cvt_x | pack_qkv(+corr) | pack_o ----------
// blocks [0,8192): x->bf16 ; [8192,17408): W_QKV pack ; [17408,20480): W_O.
__global__ __launch_bounds__(256) void k_prep(
    const float* __restrict__ x, unsigned short* __restrict__ X16,
    const float* __restrict__ WQ, const float* __restrict__ WK, const float* __restrict__ WV,
    const float* __restrict__ FK0, const float* __restrict__ PK0,
    const float* __restrict__ FV0, const float* __restrict__ PV0,
    const float* __restrict__ FK1, const float* __restrict__ PK1,
    const float* __restrict__ FV1, const float* __restrict__ PV1,
    unsigned short* __restrict__ WTQKV,
    const float* __restrict__ WO, unsigned short* __restrict__ WTO) {
  __shared__ float tile[32][33];
  __shared__ float Fs[32][9];
  __shared__ float Ps[8][32];
  const int bid = blockIdx.x;
  const int tid = threadIdx.x;
  if (bid < 8192) {                       // ---- x -> bf16 (float4 per thread)
    int i = bid * 256 + tid;
    float4 v = ((const float4*)x)[i];
    union { unsigned short u[4]; uint2 v2; } o;
    o.u[0] = f2bf(v.x); o.u[1] = f2bf(v.y); o.u[2] = f2bf(v.z); o.u[3] = f2bf(v.w);
    ((uint2*)X16)[i] = o.v2;
    return;
  }
  const int tx = tid & 31, ty = tid >> 5;
  if (bid < 17408) {                      // ---- W_QKV transpose + corrections
    int t = bid - 8192;
    int k0 = (t & 63) * 32, n0 = (t >> 6) * 32;
    const float* src; int nboff;
    if (n0 < 1536)      { src = WQ; nboff = n0; }
    else if (n0 < 3072) { src = WK; nboff = n0 - 1536; }
    else                { src = WV; nboff = n0 - 3072; }
#pragma unroll
    for (int j = 0; j < 4; ++j) {
      int kk = ty + j * 8;
      tile[kk][tx] = src[(size_t)(k0 + kk) * 1536 + nboff + tx];
    }
    int corrsel = 0; const float* Fsrc = nullptr; const float* Psrc = nullptr;
    int h = 0, d0 = 0, fs = 0, koff = 0;
    if (n0 >= 1536) {
      bool isK = (n0 < 3072);
      int np0 = isK ? (n0 - 1536) : (n0 - 3072);
      if (np0 < 256) {
        if (k0 >= 256) { corrsel = 1; Fsrc = isK ? FK0 : FV0; Psrc = isK ? PK0 : PV0;
                         h = np0 >> 6; d0 = np0 & 63; fs = 32; koff = k0 - 256; }
      } else if (np0 < 768) {
        if (k0 >= 1024) { corrsel = 1; Fsrc = isK ? FK1 : FV1; Psrc = isK ? PK1 : PV1;
                          h = (np0 - 256) >> 6; d0 = (np0 - 256) & 63; fs = 64; koff = k0 - 1024; }
      }
    }
    if (corrsel) {
      Fs[tid >> 3][tid & 7] = Fsrc[(size_t)(koff + (tid >> 3)) * fs + h * 8 + (tid & 7)];
      Ps[tid >> 5][tid & 31] = Psrc[h * 512 + (tid >> 5) * 64 + d0 + (tid & 31)];
    }
    __syncthreads();
#pragma unroll
    for (int j = 0; j < 4; ++j) {
      int nn = ty + j * 8;
      float v = tile[tx][nn];
      if (corrsel) {
        float c = 0.f;
#pragma unroll
        for (int r = 0; r < 8; ++r) c += Fs[tx][r] * Ps[r][nn];
        v += c;
      }
      WTQKV[(size_t)(n0 + nn) * 2048 + k0 + tx] = f2bf(v);
    }
  } else {                                // ---- W_O transpose
    int t = bid - 17408;
    int k0 = (t % 48) * 32, n0 = (t / 48) * 32;
#pragma unroll
    for (int j = 0; j < 4; ++j)
      tile[ty + j * 8][tx] = WO[(size_t)(k0 + ty + j * 8) * 2048 + n0 + tx];
    __syncthreads();
#pragma unroll
    for (int j = 0; j < 4; ++j)
      WTO[(size_t)(n0 + ty + j * 8) * 1536 + k0 + tx] = f2bf(tile[tx][ty + j * 8]);
  }
}

// ---------------- 4/6. GEMM BK=64, Keff per column block, XCD-chunked -------
// MODE 0: QKV (1152 blocks = 8 XCD x 144). Long class dispatches V-cols first.
//   Q/K cols (bn<3072) -> QK (LD 3072); V cols (bn>=3072) -> VT[b][d][t]
//   via in-LDS 64x64 transpose.
// MODE 1: out (512 blocks = 8 x 64) -> f32 C (LD 2048).
template <bool OUT_BF16, int MODE>
__global__ __launch_bounds__(256) void k_gemm_bt(const unsigned short* __restrict__ A,
                                                 const unsigned short* __restrict__ Bt,
                                                 void* __restrict__ C, int M, int N, int K,
                                                 unsigned short* __restrict__ VTout) {
  __shared__ unsigned short As[128 * 64];
  __shared__ unsigned short Bs[128 * 64];
  const int tid = threadIdx.x;
  const int wave = tid >> 6, lane = tid & 63;
  const int qd = lane >> 4, ln = lane & 15;
  const int idx = blockIdx.x;
  const int xcd = idx & 7, r = idx >> 3;
  int bx, by;
  if (MODE == 0) {
    if (r < 120) {                 // long: Keff=2048; scol inverted => V first
      int L = xcd * 120 + r;
      int scol = L / 192, q = L % 192;
      by = q / 6; bx = 6 + (4 - scol) * 6 + q % 6;
    } else {
      int ms = xcd * 24 + (r - 120);          // 0..191
      if (ms < 128) { bx = 2 + (ms & 3); by = ms >> 2; }   // mid: Keff=1024
      else          { int sh = ms - 128; bx = sh & 1; by = sh >> 1; } // short
    }
  } else {
    if (r < 32) {                  // long: Keff=1536, 256 blocks = 2 scol x (4bx x 32by)
      int L = xcd * 32 + r;
      int scol = L >> 7, q = L & 127;
      by = q >> 2; bx = 8 + scol * 4 + (q & 3);
    } else if (r < 56) {
      int m = xcd * 24 + (r - 32);            // 0..191, mid: Keff=768
      bx = 2 + m % 6; by = m / 6;
    } else {
      int sh = xcd * 8 + (r - 56);            // 0..63, short: Keff=256
      bx = sh & 1; by = sh >> 1;
    }
  }
  const int bm = by * 128, bn = bx * 128;
  const int wr = wave >> 1, wc = wave & 1;
  int Keff;
  if (MODE == 0) Keff = (bn < 256) ? 256 : (bn < 768 ? 1024 : 2048);
  else           Keff = (bn < 256) ? 256 : (bn < 1024 ? 768 : 1536);
  floatx4 acc[4][4];
#pragma unroll
  for (int i = 0; i < 4; ++i)
#pragma unroll
    for (int j = 0; j < 4; ++j) acc[i][j] = (floatx4){0.f, 0.f, 0.f, 0.f};
  const int rl = lane >> 3;                        // row mod 8
  const int sg = (lane & 7) ^ rl;                  // swizzled source group
  const unsigned short* gA = A + (size_t)(bm + wave * 32 + rl) * K + sg * 8;
  const unsigned short* gB = Bt + (size_t)(bn + wave * 32 + rl) * K + sg * 8;
  unsigned short* lA = As + wave * 2048;
  unsigned short* lB = Bs + wave * 2048;
  const int l7 = ln & 7;
  for (int k0 = 0; k0 < Keff; k0 += 64) {
    __syncthreads();
#pragma unroll
    for (int i = 0; i < 4; ++i) {
      gload_lds16(gA + (size_t)8 * i * K + k0, lA + i * 512);
      gload_lds16(gB + (size_t)8 * i * K + k0, lB + i * 512);
    }
    __syncthreads();
#pragma unroll
    for (int h = 0; h < 2; ++h) {
      bf16x8 af[4], bfr[4];
#pragma unroll
      for (int mi = 0; mi < 4; ++mi)
        af[mi] = *(const bf16x8*)(As + (wr * 64 + mi * 16 + ln) * 64 + ((h * 4 + qd) ^ l7) * 8);
#pragma unroll
      for (int ni = 0; ni < 4; ++ni)
        bfr[ni] = *(const bf16x8*)(Bs + (wc * 64 + ni * 16 + ln) * 64 + ((h * 4 + qd) ^ l7) * 8);
#pragma unroll
      for (int mi = 0; mi < 4; ++mi)
#pragma unroll
        for (int ni = 0; ni < 4; ++ni)
          acc[mi][ni] = __builtin_amdgcn_mfma_f32_16x16x32_bf16(af[mi], bfr[ni], acc[mi][ni], 0, 0, 0);
    }
  }
  if (MODE == 0 && bn >= 3072) {
    // ---- V block: transpose 128x128 in LDS (per-wave 64x64), store VT[b][d][t].
    __syncthreads();                       // all waves done reading As/Bs
    unsigned short* tw = (wave < 2) ? (As + wave * 4096) : (Bs + (wave - 2) * 4096);
#pragma unroll
    for (int mi = 0; mi < 4; ++mi)
#pragma unroll
      for (int ni = 0; ni < 4; ++ni) {
        union { unsigned short u[4]; uint2 v; } p;
#pragma unroll
        for (int rr = 0; rr < 4; ++rr) p.u[rr] = f2bf(acc[mi][ni][rr]);
        int d = ni * 16 + ln;
        int c = mi * 2 + (qd >> 1);
        *(uint2*)(tw + d * 64 + ((c ^ (ln & 7)) << 3) + ((qd & 1) << 2)) = p.v;
      }
    __asm__ volatile("s_waitcnt lgkmcnt(0)" ::: "memory");
    const int a = lane >> 3, bl = lane & 7;
    const int bb = bm >> 10, tt0 = bm & 1023;
    const int dbase = (bn - 3072) + wc * 64;
    const int tg = tt0 + wr * 64 + bl * 8;
#pragma unroll
    for (int i = 0; i < 8; ++i) {
      int d = a + 8 * i;
      uint4 v = *(const uint4*)(tw + d * 64 + ((bl ^ a) << 3));
      *(uint4*)(VTout + ((size_t)(bb * 1536 + dbase + d)) * 1024 + tg) = v;
    }
  } else {
#pragma unroll
    for (int mi = 0; mi < 4; ++mi)
#pragma unroll
      for (int r2 = 0; r2 < 4; ++r2) {
        int row = bm + wr * 64 + mi * 16 + qd * 4 + r2;
#pragma unroll
        for (int ni = 0; ni < 4; ++ni) {
          int col = bn + wc * 64 + ni * 16 + ln;
          if (OUT_BF16)
            ((unsigned short*)C)[(size_t)row * N + col] = f2bf(acc[mi][ni][r2]);
          else
            ((float*)C)[(size_t)row * N + col] = acc[mi][ni][r2];
        }
      }
  }
}

// ---------------- 5. causal flash attention, 128q x 128k tiles --------------
// grid (24 heads, 4 batch, 8 qtiles): qtile slowest => all 8 qtiles of a
// (head,batch) on one XCD (96%8==0). qb=7-z: LPT. QK buffer LD 3072.
// T14 async-stage (reg-staged K/V, issue-early). P-pack via v_cvt_pk_bf16_f32.
#define LDP 136
__global__ __launch_bounds__(256) void k_attn(const unsigned short* __restrict__ QKV,
                                              const unsigned short* __restrict__ VT,
                                              unsigned short* __restrict__ Oout) {
  __shared__ unsigned short Ks[128 * 64];     // [key][d], 8-grp XOR swizzle
  __shared__ unsigned short VTs[64 * 128];    // [d][key], 16-grp XOR swizzle
  __shared__ unsigned short Pl[4][16 * LDP];  // wave-private P staging
  const int tid = threadIdx.x;
  const int wave = tid >> 6, lane = tid & 63;
  const int qd = lane >> 4, ln = lane & 15;
  const int gh = blockIdx.x, b = blockIdx.y;
  const int qb = 7 - (int)blockIdx.z;                    // big qtiles first
  const int T = 1024, LD = 3072;
  const size_t rowbase = (size_t)b * T * LD;
  const int qcol = 64 * gh, kcol = 1536 + 64 * gh;
  const unsigned short* VTg = VT + ((size_t)b * 1536 + 64 * gh) * 1024;
  const float SCALE = 0.18033688f;  // 1/sqrt(64) * log2(e)
  const int q0 = qb * 128 + wave * 16;       // frag j adds j*64

  bf16x8 aq[2][2];
#pragma unroll
  for (int j = 0; j < 2; ++j) {
    const unsigned short* qp = QKV + rowbase + (size_t)(q0 + j * 64 + ln) * LD + qcol;
    aq[j][0] = *(const bf16x8*)(qp + qd * 8);
    aq[j][1] = *(const bf16x8*)(qp + 32 + qd * 8);
  }
  floatx4 Oacc[2][4];
#pragma unroll
  for (int j = 0; j < 2; ++j)
#pragma unroll
    for (int i = 0; i < 4; ++i) Oacc[j][i] = (floatx4){0.f, 0.f, 0.f, 0.f};
  float l_lane[2] = {0.f, 0.f};

  // K staging: wave owns rows [wave*32, +32); V staging: d-rows [wave*16,+16)
  const int rk = lane >> 3;                   // 0..7
  const int gk = ((lane & 7) ^ rk) * 8;       // swizzled source group (8-grp)
  const unsigned short* gK = QKV + rowbase + (size_t)(wave * 32 + rk) * LD + kcol + gk;
  unsigned short* lK = Ks + wave * 32 * 64;
  const int rv = lane >> 4;                   // 0..3
  const int cv = lane & 15;
  unsigned short* lV = VTs + wave * 16 * 128;
  const unsigned short* gVrow[4];
  int gvcol[4];
#pragma unroll
  for (int i = 0; i < 4; ++i) {
    int d = wave * 16 + 4 * i + rv;
    gVrow[i] = VTg + (size_t)d * 1024;
    gvcol[i] = (cv ^ (4 * i + rv)) * 8;       // 16-grp swizzle by d&15
  }
  const int l7 = ln & 7;

  // ---- reg-staged tiles (time-shared reg block, T14/T16)
  bf16x8 kr[4], vr[4];
#pragma unroll
  for (int i = 0; i < 4; ++i) {
    kr[i] = *(const bf16x8*)(gK + (size_t)(8 * i) * LD);
    vr[i] = *(const bf16x8*)(gVrow[i] + gvcol[i]);
  }

  for (int jt = 0; jt <= qb; ++jt) {
    const int jk = jt * 128;
    const bool diag = (jt == qb);
    __syncthreads();                        // prior reads done; vmcnt drained
#pragma unroll
    for (int i = 0; i < 4; ++i) {
      *(bf16x8*)(lK + i * 512 + lane * 8) = kr[i];
      *(bf16x8*)(lV + i * 512 + lane * 8) = vr[i];
    }
    __syncthreads();                        // publish
    if (jt < qb) {
      const int nk = jk + 128;
#pragma unroll
      for (int i = 0; i < 4; ++i) {
        kr[i] = *(const bf16x8*)(gK + (size_t)(nk + 8 * i) * LD);
        vr[i] = *(const bf16x8*)(gVrow[i] + nk + gvcol[i]);
      }
    }

#pragma unroll
    for (int j = 0; j < 2; ++j) {
      const bool dj0 = diag && (j == 0);
      const int hmax = dj0 ? 4 : 8;
      // S^T = K Q^T : A = K[key][d] (frag h = keys h*16..+16), B = Q
      floatx4 Sc[8];
#pragma unroll
      for (int h = 0; h < 8; ++h) {
        if (h >= hmax) continue;
        Sc[h] = (floatx4){0.f, 0.f, 0.f, 0.f};
        bf16x8 a0 = *(const bf16x8*)(Ks + (h * 16 + ln) * 64 + (qd ^ l7) * 8);
        bf16x8 a1 = *(const bf16x8*)(Ks + (h * 16 + ln) * 64 + ((4 + qd) ^ l7) * 8);
        Sc[h] = __builtin_amdgcn_mfma_f32_16x16x32_bf16(a0, aq[j][0], Sc[h], 0, 0, 0);
        Sc[h] = __builtin_amdgcn_mfma_f32_16x16x32_bf16(a1, aq[j][1], Sc[h], 0, 0, 0);
      }
      const int qrow = q0 + j * 64 + ln;
      unsigned short* pw = Pl[wave];
#pragma unroll
      for (int h = 0; h < 8; ++h) {
        if (h >= hmax) continue;
        float pv0, pv1, pv2, pv3;
        {
          float p;
#define ATTN_P(RR, DST)                                                        \
          p = __builtin_amdgcn_exp2f(fminf(Sc[h][RR] * SCALE, 80.f));          \
          if (diag && (j == 0 || h >= 4)) {                                    \
            int key = jk + h * 16 + qd * 4 + RR;                               \
            if (key > qrow) p = 0.f;                                           \
          }                                                                    \
          l_lane[j] += p; DST = p;
          ATTN_P(0, pv0) ATTN_P(1, pv1) ATTN_P(2, pv2) ATTN_P(3, pv3)
#undef ATTN_P
        }
        uint2 pk2;
        asm("v_cvt_pk_bf16_f32 %0, %1, %2" : "=v"(pk2.x) : "v"(pv0), "v"(pv1));
        asm("v_cvt_pk_bf16_f32 %0, %1, %2" : "=v"(pk2.y) : "v"(pv2), "v"(pv3));
        *(uint2*)(pw + ln * LDP + h * 16 + qd * 4) = pk2;
      }
      __asm__ volatile("s_waitcnt lgkmcnt(0)" ::: "memory");
      const int smax = dj0 ? 2 : 4;
      bf16x8 pa[4];
#pragma unroll
      for (int s = 0; s < 4; ++s) {
        if (s >= smax) continue;
        pa[s] = *(const bf16x8*)(pw + ln * LDP + s * 32 + qd * 8);
      }
#pragma unroll
      for (int nc = 0; nc < 4; ++nc) {
        const int d = nc * 16 + ln;
#pragma unroll
        for (int s = 0; s < 4; ++s) {
          if (s >= smax) continue;
          bf16x8 bv = *(const bf16x8*)(VTs + d * 128 + (((s * 4 + qd) ^ ln) & 15) * 8);
          Oacc[j][nc] = __builtin_amdgcn_mfma_f32_16x16x32_bf16(pa[s], bv, Oacc[j][nc], 0, 0, 0);
        }
      }
    }
  }
  // l: sum the 4 qd-groups per ln, then normalize + store
#pragma unroll
  for (int j = 0; j < 2; ++j) {
    float l = l_lane[j];
    l += __shfl_xor(l, 16, 64);
    l += __shfl_xor(l, 32, 64);
#pragma unroll
    for (int r = 0; r < 4; ++r) {
      float inv = 1.0f / __shfl(l, qd * 4 + r, 64);
      size_t row = (size_t)b * T + q0 + j * 64 + qd * 4 + r;
#pragma unroll
      for (int nc = 0; nc < 4; ++nc)
        Oout[row * 1536 + 64 * gh + nc * 16 + ln] = f2bf(Oacc[j][nc][r] * inv);
    }
  }
}

// ---------------------------------------------------------------------------
extern "C" void kernel_launch(void* const* d_in, const int* in_sizes, int n_in,
                              void* d_out, int out_size, void* d_ws, size_t ws_size,
                              hipStream_t stream) {
  (void)in_sizes; (void)n_in; (void)out_size; (void)ws_size;
  const float* x   = (const float*)d_in[0];
  const float* WQ  = (const float*)d_in[1];
  const float* WK  = (const float*)d_in[2];
  const float* WV  = (const float*)d_in[3];
  const float* WO  = (const float*)d_in[4];
  const float* FK0 = (const float*)d_in[5];
  const float* PK0 = (const float*)d_in[6];
  const float* FV0 = (const float*)d_in[7];
  const float* PV0 = (const float*)d_in[8];
  const float* FK1 = (const float*)d_in[9];
  const float* PK1 = (const float*)d_in[10];
  const float* FV1 = (const float*)d_in[11];
  const float* PV1 = (const float*)d_in[12];

  char* ws = (char*)d_ws;
  unsigned short* X16   = (unsigned short*)(ws + 0);          // 16.0 MB
  unsigned short* WTQKV = (unsigned short*)(ws + 16777216);   // 18.0 MB
  unsigned short* QK    = (unsigned short*)(ws + 35651584);   // 24.0 MB (LD 3072)
  unsigned short* VT    = (unsigned short*)(ws + 60817408);   // 12.0 MB
  unsigned short* ATT   = (unsigned short*)(ws + 73400320);   // 12.0 MB
  unsigned short* WTO   = (unsigned short*)(ws + 85983232);   //  6.0 MB

  k_prep<<<20480, 256, 0, stream>>>(x, X16, WQ, WK, WV,
                                    FK0, PK0, FV0, PV0, FK1, PK1, FV1, PV1,
                                    WTQKV, WO, WTO);
  k_gemm_bt<true, 0><<<1152, 256, 0, stream>>>(X16, WTQKV, QK, 4096, 3072, 2048, VT);
  k_attn<<<dim3(24, 4, 8), 256, 0, stream>>>(QK, VT, ATT);
  k_gemm_bt<false, 1><<<512, 256, 0, stream>>>(ATT, WTO, d_out, 4096, 2048, 1536, nullptr);
}